// Round 9
// baseline (1849.124 us; speedup 1.0000x reference)
//
#include <hip/hip_runtime.h>
#include <hip/hip_bf16.h>

#define NN 4096
#define HD 128
#define KE 32
#define KI 20
#define BST 36   // LDS tile leading stride (32 cols + 4 pad, rows 16B-aligned)

// output element offsets
#define OFF_H   0
#define OFF_POS 524288
#define OFF_F   536576
#define OFF_S   548864
#define OFF_C   794624
#define OFF_ST  1056768

typedef unsigned short u16;
typedef unsigned long long u64;

__device__ __forceinline__ float b2f(u16 u) {
  union { unsigned int i; float f; } c; c.i = ((unsigned int)u) << 16; return c.f;
}
__device__ __forceinline__ float silu_f(float x) { return x / (1.f + __expf(-x)); }
__device__ __forceinline__ void stout(void* out, int fp32m, size_t i, float v) {
  if (fp32m) ((float*)out)[i] = v;
  else ((__hip_bfloat16*)out)[i] = __float2bfloat16(v);
}

// ---------------- dtype probe: are float inputs fp32 or bf16? ----------------
__global__ void probe_dtype(const u16* __restrict__ h, int* __restrict__ flag) {
  if (threadIdx.x == 0) atomicExch(flag, 0);
  __syncthreads();
  int bad = 0;
  for (int i = threadIdx.x; i < 8192; i += 256) {
    float v = b2f(h[i]);
    if (!(v > -1000.f && v < 1000.f)) bad = 1;  // catches NaN too
  }
  if (bad) atomicOr(flag, 1);  // 1 => inputs are fp32
}

// ---------------- convert all float tensors -> fp32 workspace ----------------
struct CvtTable {
  const void* src[25];
  int dstoff[25];
  int cnt[25];
};

__global__ void convert_all(CvtTable tab, float* __restrict__ wsf, const int* __restrict__ flag) {
  const int seg = blockIdx.y;
  const int i = blockIdx.x * 256 + threadIdx.x;
  if (i >= tab.cnt[seg]) return;
  float v;
  if (*flag) v = ((const float*)tab.src[seg])[i];
  else       v = b2f(((const u16*)tab.src[seg])[i]);
  wsf[tab.dstoff[seg] + i] = v;
}

// ---------------- graph boundaries from sorted batch ----------------
__global__ void graph_bounds(const int* __restrict__ batch, int* __restrict__ gstart) {
  int n = blockIdx.x * 256 + threadIdx.x;
  if (n >= NN) return;
  int v = batch[n];
  int pv = (n == 0) ? -1 : batch[n - 1];
  for (int b = pv + 1; b <= v; b++) gstart[b] = n;
  if (n == NN - 1) for (int b = v + 1; b <= 32; b++) gstart[b] = NN;
}

// ---------------- exact k-NN within cutoff (one wave per node) ----------------
// Numerics identical to the round-2 passing version; empty 64-candidate chunks
// are skipped via wave-uniform guards (skipped keys are ~0ull = never selected).
__global__ __launch_bounds__(256) void neigh_kernel(
    const float* __restrict__ pos, const int* __restrict__ batch,
    const int* __restrict__ gstart, int* __restrict__ idx, int* __restrict__ cnt,
    int Ksel, float cut2) {
  const int lane = threadIdx.x & 63;
  const int i = blockIdx.x * 4 + (threadIdx.x >> 6);
  const int b = batch[i];
  const int gs = gstart[b];
  const int ge = gstart[b + 1];
  const int span = ge - gs;  // wave-uniform
  const float px = pos[i * 3 + 0], py = pos[i * 3 + 1], pz = pos[i * 3 + 2];
  u64 key[16];
#pragma unroll
  for (int tq = 0; tq < 16; tq++) {
    u64 k64 = ~0ull;
    if (tq * 64 < span) {
      int j = gs + tq * 64 + lane;
      if (j < ge && j != i) {
        float dx = px - pos[j * 3 + 0];
        float dy = py - pos[j * 3 + 1];
        float dz = pz - pos[j * 3 + 2];
        float d2 = dx * dx + dy * dy + dz * dz;
        if (d2 <= cut2) k64 = (((u64)__float_as_uint(d2)) << 32) | (unsigned int)j;
      }
    }
    key[tq] = k64;
  }
  u64 thresh = 0;  // inclusive lower bound for next extraction
  int myidx = i;   // self index for invalid slots (masked downstream)
  int mycnt = 0;
  for (int s = 0; s < Ksel; s++) {
    u64 m = ~0ull;
#pragma unroll
    for (int tq = 0; tq < 16; tq++) {
      if (tq * 64 < span) {
        u64 kk = key[tq];
        if (kk >= thresh && kk < m) m = kk;
      }
    }
    for (int off = 32; off > 0; off >>= 1) {
      u64 o = __shfl_down(m, (unsigned)off, 64);
      if (o < m) m = o;
    }
    m = __shfl(m, 0, 64);
    if (m != ~0ull) {
      if (lane == s) myidx = (int)(m & 0xffffffffu);
      mycnt++;
      thresh = m + 1;
    } else break;
  }
  if (lane < Ksel) idx[i * Ksel + lane] = myidx;
  if (lane == 0) cnt[i] = mycnt;
}

#define FMA16(W, XV)                                                          \
  acc[0][0] = fmaf(W.x, XV.x, acc[0][0]); acc[0][1] = fmaf(W.x, XV.y, acc[0][1]); \
  acc[0][2] = fmaf(W.x, XV.z, acc[0][2]); acc[0][3] = fmaf(W.x, XV.w, acc[0][3]); \
  acc[1][0] = fmaf(W.y, XV.x, acc[1][0]); acc[1][1] = fmaf(W.y, XV.y, acc[1][1]); \
  acc[1][2] = fmaf(W.y, XV.z, acc[1][2]); acc[1][3] = fmaf(W.y, XV.w, acc[1][3]); \
  acc[2][0] = fmaf(W.z, XV.x, acc[2][0]); acc[2][1] = fmaf(W.z, XV.y, acc[2][1]); \
  acc[2][2] = fmaf(W.z, XV.z, acc[2][2]); acc[2][3] = fmaf(W.z, XV.w, acc[2][3]); \
  acc[3][0] = fmaf(W.w, XV.x, acc[3][0]); acc[3][1] = fmaf(W.w, XV.y, acc[3][1]); \
  acc[3][2] = fmaf(W.w, XV.z, acc[3][2]); acc[3][3] = fmaf(W.w, XV.w, acc[3][3]);

// 4-output x 4-edge register-tiled stage core, software-pipelined:
// groups of 4 f-iterations double-buffered so the next group's 8 loads
// (4 global dwordx4 weights + 4 ds_read_b128 x) are in flight behind the
// current group's 64 fmas. Per-(e,o) fp chain identical to rounds 2/6/7:
// acc = base(o); f-ascending fmaf — bit-exact.
__device__ __forceinline__ void stage16(const float* __restrict__ Wg, int o4, int e0,
                                        const float* X, const float base[4],
                                        float res[4][4]) {
  float acc[4][4];
#pragma unroll
  for (int oj = 0; oj < 4; oj++) {
    acc[oj][0] = base[oj]; acc[oj][1] = base[oj];
    acc[oj][2] = base[oj]; acc[oj][3] = base[oj];
  }
  const float* wp = Wg + o4;
  const float* xp = X + e0;
  float4 wa[4], xa[4], wb[4], xb[4];
#pragma unroll
  for (int j = 0; j < 4; j++) {
    wa[j] = *(const float4*)(wp + (size_t)j * HD);
    xa[j] = *(const float4*)(xp + j * BST);
  }
  for (int fg = 0; fg < 112; fg += 8) {
#pragma unroll
    for (int j = 0; j < 4; j++) {
      wb[j] = *(const float4*)(wp + (size_t)(fg + 4 + j) * HD);
      xb[j] = *(const float4*)(xp + (fg + 4 + j) * BST);
    }
#pragma unroll
    for (int j = 0; j < 4; j++) { FMA16(wa[j], xa[j]) }
#pragma unroll
    for (int j = 0; j < 4; j++) {
      wa[j] = *(const float4*)(wp + (size_t)(fg + 8 + j) * HD);
      xa[j] = *(const float4*)(xp + (fg + 8 + j) * BST);
    }
#pragma unroll
    for (int j = 0; j < 4; j++) { FMA16(wb[j], xb[j]) }
  }
  // fg = 112 handled in loop tail pattern: groups 120,124 remain
#pragma unroll
  for (int j = 0; j < 4; j++) {
    wb[j] = *(const float4*)(wp + (size_t)(120 + j) * HD);
    xb[j] = *(const float4*)(xp + (120 + j) * BST);
  }
#pragma unroll
  for (int j = 0; j < 4; j++) { FMA16(wa[j], xa[j]) }   // group 116? no: wa holds 112..115
  // NOTE: after loop, wa holds group 112+? -> see loop invariant below
#pragma unroll
  for (int j = 0; j < 4; j++) {
    wa[j] = *(const float4*)(wp + (size_t)(124 + j) * HD);
    xa[j] = *(const float4*)(xp + (124 + j) * BST);
  }
#pragma unroll
  for (int j = 0; j < 4; j++) { FMA16(wb[j], xb[j]) }   // group 120
#pragma unroll
  for (int j = 0; j < 4; j++) { FMA16(wa[j], xa[j]) }   // group 124
#pragma unroll
  for (int oj = 0; oj < 4; oj++) {
    res[oj][0] = acc[oj][0]; res[oj][1] = acc[oj][1];
    res[oj][2] = acc[oj][2]; res[oj][3] = acc[oj][3];
  }
}
// Loop invariant: entering iteration fg, wa/xa hold group fg; the loop body
// computes groups fg and fg+4 and reloads wa with group fg+8. After the last
// iteration (fg=104): wa holds 112. Loop bound 112 means iterations
// fg=0,8,...,104 -> computes groups 0..108, leaves wa=112. The epilogue then
// computes 112 (first FMA16 block, labeled comment), loads/computes 120, 124.
// Wait: epilogue must also compute group 116. Corrected epilogue below is
// implemented in stage16_fix — see call sites.

// Corrected, simpler pipelined core (used by the kernel): prologue + rolled
// loop over pairs with a clean tail covering groups 112..127.
__device__ __forceinline__ void stage16c(const float* __restrict__ Wg, int o4, int e0,
                                         const float* X, const float base[4],
                                         float res[4][4]) {
  float acc[4][4];
#pragma unroll
  for (int oj = 0; oj < 4; oj++) {
    acc[oj][0] = base[oj]; acc[oj][1] = base[oj];
    acc[oj][2] = base[oj]; acc[oj][3] = base[oj];
  }
  const float* wp = Wg + o4;
  const float* xp = X + e0;
  float4 wa[4], xa[4], wb[4], xb[4];
#pragma unroll
  for (int j = 0; j < 4; j++) {
    wa[j] = *(const float4*)(wp + (size_t)j * HD);
    xa[j] = *(const float4*)(xp + j * BST);
  }
  for (int fg = 0; fg < 112; fg += 8) {
#pragma unroll
    for (int j = 0; j < 4; j++) {
      wb[j] = *(const float4*)(wp + (size_t)(fg + 4 + j) * HD);
      xb[j] = *(const float4*)(xp + (fg + 4 + j) * BST);
    }
#pragma unroll
    for (int j = 0; j < 4; j++) { FMA16(wa[j], xa[j]) }
#pragma unroll
    for (int j = 0; j < 4; j++) {
      wa[j] = *(const float4*)(wp + (size_t)(fg + 8 + j) * HD);
      xa[j] = *(const float4*)(xp + (fg + 8 + j) * BST);
    }
#pragma unroll
    for (int j = 0; j < 4; j++) { FMA16(wb[j], xb[j]) }
  }
  // tail: wa holds group 112; groups 112,116,120,124 remain
#pragma unroll
  for (int j = 0; j < 4; j++) {
    wb[j] = *(const float4*)(wp + (size_t)(116 + j) * HD);
    xb[j] = *(const float4*)(xp + (116 + j) * BST);
  }
#pragma unroll
  for (int j = 0; j < 4; j++) { FMA16(wa[j], xa[j]) }   // 112
#pragma unroll
  for (int j = 0; j < 4; j++) {
    wa[j] = *(const float4*)(wp + (size_t)(120 + j) * HD);
    xa[j] = *(const float4*)(xp + (120 + j) * BST);
  }
#pragma unroll
  for (int j = 0; j < 4; j++) { FMA16(wb[j], xb[j]) }   // 116
#pragma unroll
  for (int j = 0; j < 4; j++) {
    wb[j] = *(const float4*)(wp + (size_t)(124 + j) * HD);
    xb[j] = *(const float4*)(xp + (124 + j) * BST);
  }
#pragma unroll
  for (int j = 0; j < 4; j++) { FMA16(wa[j], xa[j]) }   // 120
#pragma unroll
  for (int j = 0; j < 4; j++) { FMA16(wb[j], xb[j]) }   // 124
#pragma unroll
  for (int oj = 0; oj < 4; oj++) {
    res[oj][0] = acc[oj][0]; res[oj][1] = acc[oj][1];
    res[oj][2] = acc[oj][2]; res[oj][3] = acc[oj][3];
  }
}

// ---------------- one EGNN layer, one block per node ----------------
__global__ __launch_bounds__(256) void egnn_layer(
    const float* __restrict__ h_in, const float* __restrict__ pos_in,
    float* __restrict__ h_out, float* __restrict__ pos_out,
    const int* __restrict__ idx, const int* __restrict__ cnt,
    const float* __restrict__ ew1, const float* __restrict__ eb1,
    const float* __restrict__ ew2, const float* __restrict__ eb2,
    const float* __restrict__ cw1, const float* __restrict__ cb1,
    const float* __restrict__ cw2,
    const float* __restrict__ nw1, const float* __restrict__ nb1,
    const float* __restrict__ nw2, const float* __restrict__ nb2) {
  __shared__ __align__(16) float bufA[HD * BST];
  __shared__ __align__(16) float bufB[HD * BST];
  __shared__ float hi_s[HD], hpart[HD], msum_s[HD], u_s[HD], red_s[256];
  __shared__ float rel_s[3][KE], d2_s[KE], mf_s[KE], ce_s[KE];
  __shared__ int idx_s[KE];

  const int i = blockIdx.x;
  const int t = threadIdx.x;

  if (t < KE) idx_s[t] = idx[i * KE + t];
  if (t >= 128) hi_s[t - 128] = h_in[(size_t)i * HD + (t - 128)];
  __syncthreads();

  const int cn = cnt[i];
  const int NCH = (cn + 3) >> 2;                    // valid 4-edge chunks (1..8)
  // round-7 mapping: og=t&31 (4-output tile), ec=t>>5 (4-edge chunk).
  // Waves own adjacent chunk pairs -> on sparse layers whole waves skip the
  // f-loop via execz (chunk pairs {0,1},{2,3},{4,5},{6,7}).
  const int og = t & 31, ec = t >> 5;
  const int o4 = og * 4, e0 = ec * 4;
  const bool active = (ec < NCH);

  if (t < KE) {
    int j = idx_s[t];
    float rx = pos_in[i * 3 + 0] - pos_in[j * 3 + 0];
    float ry = pos_in[i * 3 + 1] - pos_in[j * 3 + 1];
    float rz = pos_in[i * 3 + 2] - pos_in[j * 3 + 2];
    rel_s[0][t] = rx; rel_s[1][t] = ry; rel_s[2][t] = rz;
    d2_s[t] = rx * rx + ry * ry + rz * rz;
    mf_s[t] = (t < cn) ? 1.0f : 0.0f;
  }
  // gather hj -> bufA[f][e]
  {
    const int e = t & 31, f0 = (t >> 5) * 16;
    const int j = idx_s[e];
    const float4* src = (const float4*)(h_in + (size_t)j * HD + f0);
#pragma unroll
    for (int qq = 0; qq < 4; qq++) {
      float4 v = src[qq];
      int fb = f0 + qq * 4;
      bufA[(fb + 0) * BST + e] = v.x;
      bufA[(fb + 1) * BST + e] = v.y;
      bufA[(fb + 2) * BST + e] = v.z;
      bufA[(fb + 3) * BST + e] = v.w;
    }
  }
  // hpart[o] = hi . ew1[0:128, o]   (edge-invariant half of edge MLP1)
  {
    const int oo = t & 127, fb = (t >> 7) * 64;
    float hp = 0.f;
#pragma unroll 4
    for (int f = fb; f < fb + 64; f++) hp = fmaf(hi_s[f], ew1[f * HD + oo], hp);
    red_s[t] = hp;
  }
  __syncthreads();
  if (t < HD) hpart[t] = red_s[t] + red_s[t + 128] + eb1[t];
  __syncthreads();

  // ---- stage B: m1 = silu(hpart + hj @ ew1[128:256] + d2*ew1[256]) -> bufB ----
  if (active) {
    float base[4] = {hpart[o4], hpart[o4 + 1], hpart[o4 + 2], hpart[o4 + 3]};
    float res[4][4];
    stage16c(ew1 + 128 * HD, o4, e0, bufA, base, res);
    float4 w256 = *(const float4*)(ew1 + 256 * HD + o4);
    float w2a[4] = {w256.x, w256.y, w256.z, w256.w};
#pragma unroll
    for (int oj = 0; oj < 4; oj++) {
      float4 s;
      s.x = silu_f(fmaf(w2a[oj], d2_s[e0 + 0], res[oj][0]));
      s.y = silu_f(fmaf(w2a[oj], d2_s[e0 + 1], res[oj][1]));
      s.z = silu_f(fmaf(w2a[oj], d2_s[e0 + 2], res[oj][2]));
      s.w = silu_f(fmaf(w2a[oj], d2_s[e0 + 3], res[oj][3]));
      *(float4*)(bufB + (o4 + oj) * BST + e0) = s;
    }
  }
  __syncthreads();

  // ---- stage C: m2 = mask ? silu(m1 @ ew2 + eb2) : 0 -> bufA (pad chunks zeroed) ----
  {
    if (active) {
      float base[4] = {eb2[o4], eb2[o4 + 1], eb2[o4 + 2], eb2[o4 + 3]};
      float res[4][4];
      stage16c(ew2, o4, e0, bufB, base, res);
#pragma unroll
      for (int oj = 0; oj < 4; oj++) {
        float4 s;
        s.x = (mf_s[e0 + 0] != 0.f) ? silu_f(res[oj][0]) : 0.f;
        s.y = (mf_s[e0 + 1] != 0.f) ? silu_f(res[oj][1]) : 0.f;
        s.z = (mf_s[e0 + 2] != 0.f) ? silu_f(res[oj][2]) : 0.f;
        s.w = (mf_s[e0 + 3] != 0.f) ? silu_f(res[oj][3]) : 0.f;
        *(float4*)(bufA + (o4 + oj) * BST + e0) = s;
      }
    } else {
      // zero pad chunks so msum's add chain matches bit-exactly
      float4 z; z.x = 0.f; z.y = 0.f; z.z = 0.f; z.w = 0.f;
#pragma unroll
      for (int oj = 0; oj < 4; oj++) *(float4*)(bufA + (o4 + oj) * BST + e0) = z;
    }
  }
  __syncthreads();

  // ---- stage D: c1 = silu(m2 @ cw1 + cb1) -> bufB ----
  if (active) {
    float base[4] = {cb1[o4], cb1[o4 + 1], cb1[o4 + 2], cb1[o4 + 3]};
    float res[4][4];
    stage16c(cw1, o4, e0, bufA, base, res);
#pragma unroll
    for (int oj = 0; oj < 4; oj++) {
      float4 s;
      s.x = silu_f(res[oj][0]); s.y = silu_f(res[oj][1]);
      s.z = silu_f(res[oj][2]); s.w = silu_f(res[oj][3]);
      *(float4*)(bufB + (o4 + oj) * BST + e0) = s;
    }
  }
  __syncthreads();

  // ---- c[e] = c1[e] . cw2 ; pos update ----
  {
    const int e = t & 31, oc = t >> 5;
    float p = 0.f;
#pragma unroll 4
    for (int u = 0; u < 16; u++) {
      int oo = oc * 16 + u;
      p = fmaf(bufB[oo * BST + e], cw2[oo], p);
    }
    red_s[t] = p;
  }
  __syncthreads();
  if (t < KE) {
    float c = 0.f;
#pragma unroll
    for (int u = 0; u < 8; u++) c += red_s[u * 32 + t];
    ce_s[t] = (t < cn) ? c : 0.f;
  }
  __syncthreads();
  if (t < 3) {
    float s = 0.f;
#pragma unroll
    for (int e = 0; e < KE; e++) s = fmaf(rel_s[t][e], ce_s[e], s);
    float cntf = fmaxf((float)cn, 1.f);
    pos_out[i * 3 + t] = pos_in[i * 3 + t] + s / cntf;
  }
  // ---- msum[o] = sum_e m2[e][o] ----
  {
    const int oo = t & 127, ehh = t >> 7;
    float p = 0.f;
#pragma unroll
    for (int u = 0; u < 16; u++) p += bufA[oo * BST + ehh * 16 + u];
    red_s[t] = p;
  }
  __syncthreads();
  if (t < HD) msum_s[t] = red_s[t] + red_s[t + 128];
  __syncthreads();
  // ---- node MLP1 ----
  {
    const int oo = t & 127, ph = t >> 7;
    const float* src = ph ? msum_s : hi_s;
    const float* Wp = nw1 + (size_t)ph * 128 * HD + oo;
    float p = 0.f;
#pragma unroll 4
    for (int f = 0; f < 128; f++) p = fmaf(src[f], Wp[f * HD], p);
    red_s[t] = p;
  }
  __syncthreads();
  if (t < HD) u_s[t] = silu_f(red_s[t] + red_s[t + 128] + nb1[t]);
  __syncthreads();
  // ---- node MLP2 + residual ----
  {
    const int oo = t & 127, ph = t >> 7;
    const float* Wp = nw2 + (size_t)ph * 64 * HD + oo;
    float p = 0.f;
#pragma unroll 4
    for (int f = 0; f < 64; f++) p = fmaf(u_s[ph * 64 + f], Wp[f * HD], p);
    red_s[t] = p;
  }
  __syncthreads();
  if (t < HD) h_out[(size_t)i * HD + t] = hi_s[t] + red_s[t] + red_s[t + 128] + nb2[t];
}

// ---------------- final heads (per node) ----------------
__global__ __launch_bounds__(256) void heads_kernel(
    const float* __restrict__ h, const float* __restrict__ pos,
    const float* __restrict__ fw1, const float* __restrict__ fb1,
    const float* __restrict__ fw2, const float* __restrict__ fb2,
    const float* __restrict__ cw1g, const float* __restrict__ cb1g,
    const float* __restrict__ cw2g, const float* __restrict__ cb2g,
    const float* __restrict__ sw, const float* __restrict__ sb,
    const float* __restrict__ iw,
    float* __restrict__ At, float* __restrict__ Bt,
    void* __restrict__ out, const int* __restrict__ flag) {
  __shared__ float hi_s[HD], v1[HD], red_s[256];
  const int i = blockIdx.x, t = threadIdx.x;
  const int fm = *flag;
  if (t < HD) hi_s[t] = h[(size_t)i * HD + t];
  __syncthreads();
  const int o = t & 127, ph = t >> 7;
  // forces MLP1
  {
    float p = 0.f;
#pragma unroll 4
    for (int f = ph * 64; f < ph * 64 + 64; f++) p = fmaf(hi_s[f], fw1[f * HD + o], p);
    red_s[t] = p;
  }
  __syncthreads();
  if (t < HD) v1[t] = tanhf(red_s[t] + red_s[t + 128] + fb1[t]);
  __syncthreads();
  if (t < 3) {
    float p = 0.f;
    for (int f = 0; f < HD; f++) p = fmaf(v1[f], fw2[f * 3 + t], p);
    stout(out, fm, OFF_F + (size_t)i * 3 + t, p + fb2[t]);
  }
  __syncthreads();
  // conformer MLP1
  {
    float p = 0.f;
#pragma unroll 4
    for (int f = ph * 64; f < ph * 64 + 64; f++) p = fmaf(hi_s[f], cw1g[f * HD + o], p);
    red_s[t] = p;
  }
  __syncthreads();
  if (t < HD) v1[t] = fmaxf(red_s[t] + red_s[t + 128] + cb1g[t], 0.f);
  __syncthreads();
  // conformer MLP2
  {
    const int oo = t & 63, pc = t >> 6;
    float p = 0.f;
#pragma unroll 4
    for (int f = pc * 32; f < pc * 32 + 32; f++) p = fmaf(v1[f], cw2g[f * 64 + oo], p);
    red_s[t] = p;
  }
  __syncthreads();
  if (t < 64)
    stout(out, fm, OFF_C + (size_t)i * 64 + t,
          red_s[t] + red_s[t + 64] + red_s[t + 128] + red_s[t + 192] + cb2g[t]);
  __syncthreads();
  // steric
  if (t < HD) red_s[t] = hi_s[t] * sw[t];
  __syncthreads();
  if (t == 0) {
    float p = 0.f;
    for (int f = 0; f < HD; f++) p += red_s[f];
    stout(out, fm, OFF_ST + (size_t)i, p + sb[0]);
  }
  __syncthreads();
  // interaction head per-node dots
  {
    const int g = t >> 5, l = t & 31;
    float p = 0.f;
    if (g < 6) {
      const int tt = g >> 1, half = g & 1;
#pragma unroll
      for (int r2 = 0; r2 < 4; r2++)
        p = fmaf(hi_s[l * 4 + r2], iw[tt * 258 + half * 128 + l * 4 + r2], p);
    }
    red_s[t] = p;
  }
  __syncthreads();
  if (t < 6) {
    float p = 0.f;
    for (int l = 0; l < 32; l++) p += red_s[t * 32 + l];
    const int tt = t >> 1;
    if ((t & 1) == 0) At[tt * NN + i] = p;
    else Bt[tt * NN + i] = p;
  }
  if (t < HD) stout(out, fm, OFF_H + (size_t)i * HD + t, hi_s[t]);
  if (t >= 128 && t < 131) stout(out, fm, OFF_POS + (size_t)i * 3 + (t - 128), pos[i * 3 + (t - 128)]);
}

// ---------------- interaction scores ----------------
__global__ void scores_kernel(const float* __restrict__ pos, const int* __restrict__ idx2,
                              const int* __restrict__ cnt2, const float* __restrict__ At,
                              const float* __restrict__ Bt, const float* __restrict__ iw,
                              const float* __restrict__ ib, void* __restrict__ out,
                              const int* __restrict__ flag) {
  int tid = blockIdx.x * 256 + threadIdx.x;
  if (tid >= 3 * NN * KI) return;
  const int fm = *flag;
  const int tt = tid / (NN * KI);
  const int r = tid % (NN * KI);
  const int n = r / KI;
  const int k = r % KI;
  float v = 0.f;
  if (k < cnt2[n]) {
    int j = idx2[n * KI + k];
    float dx = pos[n * 3 + 0] - pos[j * 3 + 0];
    float dy = pos[n * 3 + 1] - pos[j * 3 + 1];
    float dz = pos[n * 3 + 2] - pos[j * 3 + 2];
    float d2 = dx * dx + dy * dy + dz * dz;
    float dist = sqrtf(d2 + 1e-12f);
    float s = At[tt * NN + n] + Bt[tt * NN + j] + dist * iw[tt * 258 + 256] +
              (dist * 0.1f) * iw[tt * 258 + 257] + ib[tt];
    v = 1.f / (1.f + __expf(-s));
  }
  stout(out, fm, OFF_S + (size_t)tid, v);
}

extern "C" void kernel_launch(void* const* d_in, const int* in_sizes, int n_in,
                              void* d_out, int out_size, void* d_ws, size_t ws_size,
                              hipStream_t stream) {
  (void)in_sizes; (void)n_in; (void)out_size; (void)ws_size;

  float* wsf = (float*)d_ws;
  float* h_a = wsf + 0;             // 524288
  float* pos_a = wsf + 524288;      // 12288
  float* h_b = wsf + 536576;        // 524288
  float* pos_b = wsf + 1060864;     // 12288
  float* At = wsf + 1073152;        // 12288
  float* Bt = wsf + 1085440;        // 12288
  const int W0 = 1097728;

  static const int wcnt[23] = {197376, 768, 98304, 768, 98304, 768, 768,
                               196608, 768, 98304, 768, 16384, 128, 384, 3,
                               774, 3, 16384, 128, 8192, 64, 128, 1};
  int woff[23];
  {
    int o = W0;
    for (int k = 0; k < 23; k++) { woff[k] = o; o += wcnt[k]; }
  }
  const int IOFF = woff[22] + wcnt[22];
  int* ibase = (int*)d_ws;
  int* idx1 = ibase + IOFF;
  int* cnt1 = idx1 + NN * KE;
  int* idx2 = cnt1 + NN;
  int* cnt2 = idx2 + NN * KI;
  int* gstart = cnt2 + NN;
  int* flag = gstart + 33;

  const float* EW1 = wsf + woff[0];
  const float* EB1 = wsf + woff[1];
  const float* EW2 = wsf + woff[2];
  const float* EB2 = wsf + woff[3];
  const float* CW1 = wsf + woff[4];
  const float* CB1 = wsf + woff[5];
  const float* CW2 = wsf + woff[6];
  const float* NW1 = wsf + woff[7];
  const float* NB1 = wsf + woff[8];
  const float* NW2 = wsf + woff[9];
  const float* NB2 = wsf + woff[10];
  const float* FW1 = wsf + woff[11];
  const float* FB1 = wsf + woff[12];
  const float* FW2 = wsf + woff[13];
  const float* FB2 = wsf + woff[14];
  const float* IW = wsf + woff[15];
  const float* IB = wsf + woff[16];
  const float* CW1G = wsf + woff[17];
  const float* CB1G = wsf + woff[18];
  const float* CW2G = wsf + woff[19];
  const float* CB2G = wsf + woff[20];
  const float* SW = wsf + woff[21];
  const float* SB = wsf + woff[22];

  probe_dtype<<<1, 256, 0, stream>>>((const u16*)d_in[0], flag);

  CvtTable tab;
  tab.src[0] = d_in[0]; tab.dstoff[0] = 0;       tab.cnt[0] = NN * HD;
  tab.src[1] = d_in[1]; tab.dstoff[1] = 524288;  tab.cnt[1] = NN * 3;
  for (int k = 0; k < 23; k++) {
    tab.src[2 + k] = d_in[3 + k];
    tab.dstoff[2 + k] = woff[k];
    tab.cnt[2 + k] = wcnt[k];
  }
  {
    dim3 g((NN * HD + 255) / 256, 25, 1);
    convert_all<<<g, 256, 0, stream>>>(tab, wsf, flag);
  }

  const int* batch = (const int*)d_in[2];
  graph_bounds<<<NN / 256, 256, 0, stream>>>(batch, gstart);

  const float cut2s[3] = {9.f, 36.f, 100.f};
  float *hin = h_a, *pin = pos_a, *hout = h_b, *pout = pos_b;
  for (int l = 0; l < 6; l++) {
    if ((l & 1) == 0)
      neigh_kernel<<<NN / 4, 256, 0, stream>>>(pin, batch, gstart, idx1, cnt1, KE, cut2s[l >> 1]);
    egnn_layer<<<NN, 256, 0, stream>>>(
        hin, pin, hout, pout, idx1, cnt1,
        EW1 + (size_t)l * 257 * HD, EB1 + (size_t)l * HD,
        EW2 + (size_t)l * HD * HD, EB2 + (size_t)l * HD,
        CW1 + (size_t)l * HD * HD, CB1 + (size_t)l * HD,
        CW2 + (size_t)l * HD,
        NW1 + (size_t)l * 256 * HD, NB1 + (size_t)l * HD,
        NW2 + (size_t)l * HD * HD, NB2 + (size_t)l * HD);
    float* th = hin; hin = hout; hout = th;
    float* tp = pin; pin = pout; pout = tp;
  }
  neigh_kernel<<<NN / 4, 256, 0, stream>>>(pin, batch, gstart, idx2, cnt2, KI, 100.f);
  heads_kernel<<<NN, 256, 0, stream>>>(hin, pin, FW1, FB1, FW2, FB2, CW1G, CB1G, CW2G, CB2G,
                                       SW, SB, IW, At, Bt, d_out, flag);
  scores_kernel<<<(3 * NN * KI + 255) / 256, 256, 0, stream>>>(
      pin, idx2, cnt2, At, Bt, IW, IB, d_out, flag);
}

// Round 10
// 1683.045 us; speedup vs baseline: 1.0987x; 1.0987x over previous
//
#include <hip/hip_runtime.h>
#include <hip/hip_bf16.h>

#define NN 4096
#define HD 128
#define KE 32
#define KI 20
#define BST 36   // LDS tile leading stride (32 cols + 4 pad, rows 16B-aligned)

// output element offsets
#define OFF_H   0
#define OFF_POS 524288
#define OFF_F   536576
#define OFF_S   548864
#define OFF_C   794624
#define OFF_ST  1056768

typedef unsigned short u16;
typedef unsigned long long u64;

__device__ __forceinline__ float b2f(u16 u) {
  union { unsigned int i; float f; } c; c.i = ((unsigned int)u) << 16; return c.f;
}
__device__ __forceinline__ float silu_f(float x) { return x / (1.f + __expf(-x)); }
__device__ __forceinline__ void stout(void* out, int fp32m, size_t i, float v) {
  if (fp32m) ((float*)out)[i] = v;
  else ((__hip_bfloat16*)out)[i] = __float2bfloat16(v);
}

// ---------------- dtype probe: are float inputs fp32 or bf16? ----------------
__global__ void probe_dtype(const u16* __restrict__ h, int* __restrict__ flag) {
  if (threadIdx.x == 0) atomicExch(flag, 0);
  __syncthreads();
  int bad = 0;
  for (int i = threadIdx.x; i < 8192; i += 256) {
    float v = b2f(h[i]);
    if (!(v > -1000.f && v < 1000.f)) bad = 1;  // catches NaN too
  }
  if (bad) atomicOr(flag, 1);  // 1 => inputs are fp32
}

// ---------------- convert all float tensors -> fp32 workspace ----------------
struct CvtTable {
  const void* src[25];
  int dstoff[25];
  int cnt[25];
};

__global__ void convert_all(CvtTable tab, float* __restrict__ wsf, const int* __restrict__ flag) {
  const int seg = blockIdx.y;
  const int i = blockIdx.x * 256 + threadIdx.x;
  if (i >= tab.cnt[seg]) return;
  float v;
  if (*flag) v = ((const float*)tab.src[seg])[i];
  else       v = b2f(((const u16*)tab.src[seg])[i]);
  wsf[tab.dstoff[seg] + i] = v;
}

// ---------------- graph boundaries from sorted batch ----------------
__global__ void graph_bounds(const int* __restrict__ batch, int* __restrict__ gstart) {
  int n = blockIdx.x * 256 + threadIdx.x;
  if (n >= NN) return;
  int v = batch[n];
  int pv = (n == 0) ? -1 : batch[n - 1];
  for (int b = pv + 1; b <= v; b++) gstart[b] = n;
  if (n == NN - 1) for (int b = v + 1; b <= 32; b++) gstart[b] = NN;
}

// ---------------- exact k-NN within cutoff (one wave per node) ----------------
// Numerics identical to the round-2 passing version; empty 64-candidate chunks
// are skipped via wave-uniform guards (skipped keys are ~0ull = never selected).
__global__ __launch_bounds__(256) void neigh_kernel(
    const float* __restrict__ pos, const int* __restrict__ batch,
    const int* __restrict__ gstart, int* __restrict__ idx, int* __restrict__ cnt,
    int Ksel, float cut2) {
  const int lane = threadIdx.x & 63;
  const int i = blockIdx.x * 4 + (threadIdx.x >> 6);
  const int b = batch[i];
  const int gs = gstart[b];
  const int ge = gstart[b + 1];
  const int span = ge - gs;  // wave-uniform
  const float px = pos[i * 3 + 0], py = pos[i * 3 + 1], pz = pos[i * 3 + 2];
  u64 key[16];
#pragma unroll
  for (int tq = 0; tq < 16; tq++) {
    u64 k64 = ~0ull;
    if (tq * 64 < span) {
      int j = gs + tq * 64 + lane;
      if (j < ge && j != i) {
        float dx = px - pos[j * 3 + 0];
        float dy = py - pos[j * 3 + 1];
        float dz = pz - pos[j * 3 + 2];
        float d2 = dx * dx + dy * dy + dz * dz;
        if (d2 <= cut2) k64 = (((u64)__float_as_uint(d2)) << 32) | (unsigned int)j;
      }
    }
    key[tq] = k64;
  }
  u64 thresh = 0;  // inclusive lower bound for next extraction
  int myidx = i;   // self index for invalid slots (masked downstream)
  int mycnt = 0;
  for (int s = 0; s < Ksel; s++) {
    u64 m = ~0ull;
#pragma unroll
    for (int tq = 0; tq < 16; tq++) {
      if (tq * 64 < span) {
        u64 kk = key[tq];
        if (kk >= thresh && kk < m) m = kk;
      }
    }
    for (int off = 32; off > 0; off >>= 1) {
      u64 o = __shfl_down(m, (unsigned)off, 64);
      if (o < m) m = o;
    }
    m = __shfl(m, 0, 64);
    if (m != ~0ull) {
      if (lane == s) myidx = (int)(m & 0xffffffffu);
      mycnt++;
      thresh = m + 1;
    } else break;
  }
  if (lane < Ksel) idx[i * Ksel + lane] = myidx;
  if (lane == 0) cnt[i] = mycnt;
}

// 4-output x 4-edge register-tiled stage core (round-7 verified optimum).
// Per-(e,o) fp chain identical to rounds 2/6/7: acc = base(o); f-ascending fmaf.
// x from LDS (1 ds_read_b128/f, broadcast), w from global (1 dwordx4/f).
// NOTE: keep VGPR <= 64 — waves/CU halve past 64 (m69); round-9's manual
// pipelining pushed VGPR to 88 and regressed 288 -> 321 us. unroll 4 is the
// sweet spot: compiler interleaves loads/fmas at 52 VGPR with 8 waves/SIMD.
__device__ __forceinline__ void stage16(const float* __restrict__ Wg, int o4, int e0,
                                        const float* X, const float base[4],
                                        float res[4][4]) {
  float acc[4][4];
#pragma unroll
  for (int oj = 0; oj < 4; oj++) {
    acc[oj][0] = base[oj]; acc[oj][1] = base[oj];
    acc[oj][2] = base[oj]; acc[oj][3] = base[oj];
  }
  const float* wp = Wg + o4;
#pragma unroll 4
  for (int f = 0; f < HD; f++) {
    float4 w = *(const float4*)(wp + (size_t)f * HD);
    float4 x = *(const float4*)(X + f * BST + e0);
    acc[0][0] = fmaf(w.x, x.x, acc[0][0]); acc[0][1] = fmaf(w.x, x.y, acc[0][1]);
    acc[0][2] = fmaf(w.x, x.z, acc[0][2]); acc[0][3] = fmaf(w.x, x.w, acc[0][3]);
    acc[1][0] = fmaf(w.y, x.x, acc[1][0]); acc[1][1] = fmaf(w.y, x.y, acc[1][1]);
    acc[1][2] = fmaf(w.y, x.z, acc[1][2]); acc[1][3] = fmaf(w.y, x.w, acc[1][3]);
    acc[2][0] = fmaf(w.z, x.x, acc[2][0]); acc[2][1] = fmaf(w.z, x.y, acc[2][1]);
    acc[2][2] = fmaf(w.z, x.z, acc[2][2]); acc[2][3] = fmaf(w.z, x.w, acc[2][3]);
    acc[3][0] = fmaf(w.w, x.x, acc[3][0]); acc[3][1] = fmaf(w.w, x.y, acc[3][1]);
    acc[3][2] = fmaf(w.w, x.z, acc[3][2]); acc[3][3] = fmaf(w.w, x.w, acc[3][3]);
  }
#pragma unroll
  for (int oj = 0; oj < 4; oj++) {
    res[oj][0] = acc[oj][0]; res[oj][1] = acc[oj][1];
    res[oj][2] = acc[oj][2]; res[oj][3] = acc[oj][3];
  }
}

// ---------------- one EGNN layer, one block per node ----------------
__global__ __launch_bounds__(256) void egnn_layer(
    const float* __restrict__ h_in, const float* __restrict__ pos_in,
    float* __restrict__ h_out, float* __restrict__ pos_out,
    const int* __restrict__ idx, const int* __restrict__ cnt,
    const float* __restrict__ ew1, const float* __restrict__ eb1,
    const float* __restrict__ ew2, const float* __restrict__ eb2,
    const float* __restrict__ cw1, const float* __restrict__ cb1,
    const float* __restrict__ cw2,
    const float* __restrict__ nw1, const float* __restrict__ nb1,
    const float* __restrict__ nw2, const float* __restrict__ nb2) {
  __shared__ __align__(16) float bufA[HD * BST];
  __shared__ __align__(16) float bufB[HD * BST];
  __shared__ float hi_s[HD], hpart[HD], msum_s[HD], u_s[HD], red_s[256];
  __shared__ float rel_s[3][KE], d2_s[KE], mf_s[KE], ce_s[KE];
  __shared__ int idx_s[KE];

  const int i = blockIdx.x;
  const int t = threadIdx.x;

  if (t < KE) idx_s[t] = idx[i * KE + t];
  if (t >= 128) hi_s[t - 128] = h_in[(size_t)i * HD + (t - 128)];
  __syncthreads();

  const int cn = cnt[i];
  const int NCH = (cn + 3) >> 2;                    // valid 4-edge chunks (1..8)
  // round-7 mapping: og=t&31 (4-output tile), ec=t>>5 (4-edge chunk).
  // Waves own adjacent chunk pairs -> on sparse layers whole waves skip the
  // f-loop via execz (chunk pairs {0,1},{2,3},{4,5},{6,7}).
  const int og = t & 31, ec = t >> 5;
  const int o4 = og * 4, e0 = ec * 4;
  const bool active = (ec < NCH);

  if (t < KE) {
    int j = idx_s[t];
    float rx = pos_in[i * 3 + 0] - pos_in[j * 3 + 0];
    float ry = pos_in[i * 3 + 1] - pos_in[j * 3 + 1];
    float rz = pos_in[i * 3 + 2] - pos_in[j * 3 + 2];
    rel_s[0][t] = rx; rel_s[1][t] = ry; rel_s[2][t] = rz;
    d2_s[t] = rx * rx + ry * ry + rz * rz;
    mf_s[t] = (t < cn) ? 1.0f : 0.0f;
  }
  // gather hj -> bufA[f][e]
  {
    const int e = t & 31, f0 = (t >> 5) * 16;
    const int j = idx_s[e];
    const float4* src = (const float4*)(h_in + (size_t)j * HD + f0);
#pragma unroll
    for (int qq = 0; qq < 4; qq++) {
      float4 v = src[qq];
      int fb = f0 + qq * 4;
      bufA[(fb + 0) * BST + e] = v.x;
      bufA[(fb + 1) * BST + e] = v.y;
      bufA[(fb + 2) * BST + e] = v.z;
      bufA[(fb + 3) * BST + e] = v.w;
    }
  }
  // hpart[o] = hi . ew1[0:128, o]   (edge-invariant half of edge MLP1)
  {
    const int oo = t & 127, fb = (t >> 7) * 64;
    float hp = 0.f;
#pragma unroll 4
    for (int f = fb; f < fb + 64; f++) hp = fmaf(hi_s[f], ew1[f * HD + oo], hp);
    red_s[t] = hp;
  }
  __syncthreads();
  if (t < HD) hpart[t] = red_s[t] + red_s[t + 128] + eb1[t];
  __syncthreads();

  // ---- stage B: m1 = silu(hpart + hj @ ew1[128:256] + d2*ew1[256]) -> bufB ----
  if (active) {
    float base[4] = {hpart[o4], hpart[o4 + 1], hpart[o4 + 2], hpart[o4 + 3]};
    float res[4][4];
    stage16(ew1 + 128 * HD, o4, e0, bufA, base, res);
    float4 w256 = *(const float4*)(ew1 + 256 * HD + o4);
    float w2a[4] = {w256.x, w256.y, w256.z, w256.w};
#pragma unroll
    for (int oj = 0; oj < 4; oj++) {
      float4 s;
      s.x = silu_f(fmaf(w2a[oj], d2_s[e0 + 0], res[oj][0]));
      s.y = silu_f(fmaf(w2a[oj], d2_s[e0 + 1], res[oj][1]));
      s.z = silu_f(fmaf(w2a[oj], d2_s[e0 + 2], res[oj][2]));
      s.w = silu_f(fmaf(w2a[oj], d2_s[e0 + 3], res[oj][3]));
      *(float4*)(bufB + (o4 + oj) * BST + e0) = s;
    }
  }
  __syncthreads();

  // ---- stage C: m2 = mask ? silu(m1 @ ew2 + eb2) : 0 -> bufA (pad chunks zeroed) ----
  {
    if (active) {
      float base[4] = {eb2[o4], eb2[o4 + 1], eb2[o4 + 2], eb2[o4 + 3]};
      float res[4][4];
      stage16(ew2, o4, e0, bufB, base, res);
#pragma unroll
      for (int oj = 0; oj < 4; oj++) {
        float4 s;
        s.x = (mf_s[e0 + 0] != 0.f) ? silu_f(res[oj][0]) : 0.f;
        s.y = (mf_s[e0 + 1] != 0.f) ? silu_f(res[oj][1]) : 0.f;
        s.z = (mf_s[e0 + 2] != 0.f) ? silu_f(res[oj][2]) : 0.f;
        s.w = (mf_s[e0 + 3] != 0.f) ? silu_f(res[oj][3]) : 0.f;
        *(float4*)(bufA + (o4 + oj) * BST + e0) = s;
      }
    } else {
      // zero pad chunks so msum's add chain matches bit-exactly
      float4 z; z.x = 0.f; z.y = 0.f; z.z = 0.f; z.w = 0.f;
#pragma unroll
      for (int oj = 0; oj < 4; oj++) *(float4*)(bufA + (o4 + oj) * BST + e0) = z;
    }
  }
  __syncthreads();

  // ---- stage D: c1 = silu(m2 @ cw1 + cb1) -> bufB ----
  if (active) {
    float base[4] = {cb1[o4], cb1[o4 + 1], cb1[o4 + 2], cb1[o4 + 3]};
    float res[4][4];
    stage16(cw1, o4, e0, bufA, base, res);
#pragma unroll
    for (int oj = 0; oj < 4; oj++) {
      float4 s;
      s.x = silu_f(res[oj][0]); s.y = silu_f(res[oj][1]);
      s.z = silu_f(res[oj][2]); s.w = silu_f(res[oj][3]);
      *(float4*)(bufB + (o4 + oj) * BST + e0) = s;
    }
  }
  __syncthreads();

  // ---- c[e] = c1[e] . cw2 ; pos update ----
  {
    const int e = t & 31, oc = t >> 5;
    float p = 0.f;
#pragma unroll 4
    for (int u = 0; u < 16; u++) {
      int oo = oc * 16 + u;
      p = fmaf(bufB[oo * BST + e], cw2[oo], p);
    }
    red_s[t] = p;
  }
  __syncthreads();
  if (t < KE) {
    float c = 0.f;
#pragma unroll
    for (int u = 0; u < 8; u++) c += red_s[u * 32 + t];
    ce_s[t] = (t < cn) ? c : 0.f;
  }
  __syncthreads();
  if (t < 3) {
    float s = 0.f;
#pragma unroll
    for (int e = 0; e < KE; e++) s = fmaf(rel_s[t][e], ce_s[e], s);
    float cntf = fmaxf((float)cn, 1.f);
    pos_out[i * 3 + t] = pos_in[i * 3 + t] + s / cntf;
  }
  // ---- msum[o] = sum_e m2[e][o] ----
  {
    const int oo = t & 127, ehh = t >> 7;
    float p = 0.f;
#pragma unroll
    for (int u = 0; u < 16; u++) p += bufA[oo * BST + ehh * 16 + u];
    red_s[t] = p;
  }
  __syncthreads();
  if (t < HD) msum_s[t] = red_s[t] + red_s[t + 128];
  __syncthreads();
  // ---- node MLP1 ----
  {
    const int oo = t & 127, ph = t >> 7;
    const float* src = ph ? msum_s : hi_s;
    const float* Wp = nw1 + (size_t)ph * 128 * HD + oo;
    float p = 0.f;
#pragma unroll 4
    for (int f = 0; f < 128; f++) p = fmaf(src[f], Wp[f * HD], p);
    red_s[t] = p;
  }
  __syncthreads();
  if (t < HD) u_s[t] = silu_f(red_s[t] + red_s[t + 128] + nb1[t]);
  __syncthreads();
  // ---- node MLP2 + residual ----
  {
    const int oo = t & 127, ph = t >> 7;
    const float* Wp = nw2 + (size_t)ph * 64 * HD + oo;
    float p = 0.f;
#pragma unroll 4
    for (int f = 0; f < 64; f++) p = fmaf(u_s[ph * 64 + f], Wp[f * HD], p);
    red_s[t] = p;
  }
  __syncthreads();
  if (t < HD) h_out[(size_t)i * HD + t] = hi_s[t] + red_s[t] + red_s[t + 128] + nb2[t];
}

// ---------------- final heads (per node) ----------------
__global__ __launch_bounds__(256) void heads_kernel(
    const float* __restrict__ h, const float* __restrict__ pos,
    const float* __restrict__ fw1, const float* __restrict__ fb1,
    const float* __restrict__ fw2, const float* __restrict__ fb2,
    const float* __restrict__ cw1g, const float* __restrict__ cb1g,
    const float* __restrict__ cw2g, const float* __restrict__ cb2g,
    const float* __restrict__ sw, const float* __restrict__ sb,
    const float* __restrict__ iw,
    float* __restrict__ At, float* __restrict__ Bt,
    void* __restrict__ out, const int* __restrict__ flag) {
  __shared__ float hi_s[HD], v1[HD], red_s[256];
  const int i = blockIdx.x, t = threadIdx.x;
  const int fm = *flag;
  if (t < HD) hi_s[t] = h[(size_t)i * HD + t];
  __syncthreads();
  const int o = t & 127, ph = t >> 7;
  // forces MLP1
  {
    float p = 0.f;
#pragma unroll 4
    for (int f = ph * 64; f < ph * 64 + 64; f++) p = fmaf(hi_s[f], fw1[f * HD + o], p);
    red_s[t] = p;
  }
  __syncthreads();
  if (t < HD) v1[t] = tanhf(red_s[t] + red_s[t + 128] + fb1[t]);
  __syncthreads();
  if (t < 3) {
    float p = 0.f;
    for (int f = 0; f < HD; f++) p = fmaf(v1[f], fw2[f * 3 + t], p);
    stout(out, fm, OFF_F + (size_t)i * 3 + t, p + fb2[t]);
  }
  __syncthreads();
  // conformer MLP1
  {
    float p = 0.f;
#pragma unroll 4
    for (int f = ph * 64; f < ph * 64 + 64; f++) p = fmaf(hi_s[f], cw1g[f * HD + o], p);
    red_s[t] = p;
  }
  __syncthreads();
  if (t < HD) v1[t] = fmaxf(red_s[t] + red_s[t + 128] + cb1g[t], 0.f);
  __syncthreads();
  // conformer MLP2
  {
    const int oo = t & 63, pc = t >> 6;
    float p = 0.f;
#pragma unroll 4
    for (int f = pc * 32; f < pc * 32 + 32; f++) p = fmaf(v1[f], cw2g[f * 64 + oo], p);
    red_s[t] = p;
  }
  __syncthreads();
  if (t < 64)
    stout(out, fm, OFF_C + (size_t)i * 64 + t,
          red_s[t] + red_s[t + 64] + red_s[t + 128] + red_s[t + 192] + cb2g[t]);
  __syncthreads();
  // steric
  if (t < HD) red_s[t] = hi_s[t] * sw[t];
  __syncthreads();
  if (t == 0) {
    float p = 0.f;
    for (int f = 0; f < HD; f++) p += red_s[f];
    stout(out, fm, OFF_ST + (size_t)i, p + sb[0]);
  }
  __syncthreads();
  // interaction head per-node dots
  {
    const int g = t >> 5, l = t & 31;
    float p = 0.f;
    if (g < 6) {
      const int tt = g >> 1, half = g & 1;
#pragma unroll
      for (int r2 = 0; r2 < 4; r2++)
        p = fmaf(hi_s[l * 4 + r2], iw[tt * 258 + half * 128 + l * 4 + r2], p);
    }
    red_s[t] = p;
  }
  __syncthreads();
  if (t < 6) {
    float p = 0.f;
    for (int l = 0; l < 32; l++) p += red_s[t * 32 + l];
    const int tt = t >> 1;
    if ((t & 1) == 0) At[tt * NN + i] = p;
    else Bt[tt * NN + i] = p;
  }
  if (t < HD) stout(out, fm, OFF_H + (size_t)i * HD + t, hi_s[t]);
  if (t >= 128 && t < 131) stout(out, fm, OFF_POS + (size_t)i * 3 + (t - 128), pos[i * 3 + (t - 128)]);
}

// ---------------- interaction scores ----------------
__global__ void scores_kernel(const float* __restrict__ pos, const int* __restrict__ idx2,
                              const int* __restrict__ cnt2, const float* __restrict__ At,
                              const float* __restrict__ Bt, const float* __restrict__ iw,
                              const float* __restrict__ ib, void* __restrict__ out,
                              const int* __restrict__ flag) {
  int tid = blockIdx.x * 256 + threadIdx.x;
  if (tid >= 3 * NN * KI) return;
  const int fm = *flag;
  const int tt = tid / (NN * KI);
  const int r = tid % (NN * KI);
  const int n = r / KI;
  const int k = r % KI;
  float v = 0.f;
  if (k < cnt2[n]) {
    int j = idx2[n * KI + k];
    float dx = pos[n * 3 + 0] - pos[j * 3 + 0];
    float dy = pos[n * 3 + 1] - pos[j * 3 + 1];
    float dz = pos[n * 3 + 2] - pos[j * 3 + 2];
    float d2 = dx * dx + dy * dy + dz * dz;
    float dist = sqrtf(d2 + 1e-12f);
    float s = At[tt * NN + n] + Bt[tt * NN + j] + dist * iw[tt * 258 + 256] +
              (dist * 0.1f) * iw[tt * 258 + 257] + ib[tt];
    v = 1.f / (1.f + __expf(-s));
  }
  stout(out, fm, OFF_S + (size_t)tid, v);
}

extern "C" void kernel_launch(void* const* d_in, const int* in_sizes, int n_in,
                              void* d_out, int out_size, void* d_ws, size_t ws_size,
                              hipStream_t stream) {
  (void)in_sizes; (void)n_in; (void)out_size; (void)ws_size;

  float* wsf = (float*)d_ws;
  float* h_a = wsf + 0;             // 524288
  float* pos_a = wsf + 524288;      // 12288
  float* h_b = wsf + 536576;        // 524288
  float* pos_b = wsf + 1060864;     // 12288
  float* At = wsf + 1073152;        // 12288
  float* Bt = wsf + 1085440;        // 12288
  const int W0 = 1097728;

  static const int wcnt[23] = {197376, 768, 98304, 768, 98304, 768, 768,
                               196608, 768, 98304, 768, 16384, 128, 384, 3,
                               774, 3, 16384, 128, 8192, 64, 128, 1};
  int woff[23];
  {
    int o = W0;
    for (int k = 0; k < 23; k++) { woff[k] = o; o += wcnt[k]; }
  }
  const int IOFF = woff[22] + wcnt[22];
  int* ibase = (int*)d_ws;
  int* idx1 = ibase + IOFF;
  int* cnt1 = idx1 + NN * KE;
  int* idx2 = cnt1 + NN;
  int* cnt2 = idx2 + NN * KI;
  int* gstart = cnt2 + NN;
  int* flag = gstart + 33;

  const float* EW1 = wsf + woff[0];
  const float* EB1 = wsf + woff[1];
  const float* EW2 = wsf + woff[2];
  const float* EB2 = wsf + woff[3];
  const float* CW1 = wsf + woff[4];
  const float* CB1 = wsf + woff[5];
  const float* CW2 = wsf + woff[6];
  const float* NW1 = wsf + woff[7];
  const float* NB1 = wsf + woff[8];
  const float* NW2 = wsf + woff[9];
  const float* NB2 = wsf + woff[10];
  const float* FW1 = wsf + woff[11];
  const float* FB1 = wsf + woff[12];
  const float* FW2 = wsf + woff[13];
  const float* FB2 = wsf + woff[14];
  const float* IW = wsf + woff[15];
  const float* IB = wsf + woff[16];
  const float* CW1G = wsf + woff[17];
  const float* CB1G = wsf + woff[18];
  const float* CW2G = wsf + woff[19];
  const float* CB2G = wsf + woff[20];
  const float* SW = wsf + woff[21];
  const float* SB = wsf + woff[22];

  probe_dtype<<<1, 256, 0, stream>>>((const u16*)d_in[0], flag);

  CvtTable tab;
  tab.src[0] = d_in[0]; tab.dstoff[0] = 0;       tab.cnt[0] = NN * HD;
  tab.src[1] = d_in[1]; tab.dstoff[1] = 524288;  tab.cnt[1] = NN * 3;
  for (int k = 0; k < 23; k++) {
    tab.src[2 + k] = d_in[3 + k];
    tab.dstoff[2 + k] = woff[k];
    tab.cnt[2 + k] = wcnt[k];
  }
  {
    dim3 g((NN * HD + 255) / 256, 25, 1);
    convert_all<<<g, 256, 0, stream>>>(tab, wsf, flag);
  }

  const int* batch = (const int*)d_in[2];
  graph_bounds<<<NN / 256, 256, 0, stream>>>(batch, gstart);

  const float cut2s[3] = {9.f, 36.f, 100.f};
  float *hin = h_a, *pin = pos_a, *hout = h_b, *pout = pos_b;
  for (int l = 0; l < 6; l++) {
    if ((l & 1) == 0)
      neigh_kernel<<<NN / 4, 256, 0, stream>>>(pin, batch, gstart, idx1, cnt1, KE, cut2s[l >> 1]);
    egnn_layer<<<NN, 256, 0, stream>>>(
        hin, pin, hout, pout, idx1, cnt1,
        EW1 + (size_t)l * 257 * HD, EB1 + (size_t)l * HD,
        EW2 + (size_t)l * HD * HD, EB2 + (size_t)l * HD,
        CW1 + (size_t)l * HD * HD, CB1 + (size_t)l * HD,
        CW2 + (size_t)l * HD,
        NW1 + (size_t)l * 256 * HD, NB1 + (size_t)l * HD,
        NW2 + (size_t)l * HD * HD, NB2 + (size_t)l * HD);
    float* th = hin; hin = hout; hout = th;
    float* tp = pin; pin = pout; pout = tp;
  }
  neigh_kernel<<<NN / 4, 256, 0, stream>>>(pin, batch, gstart, idx2, cnt2, KI, 100.f);
  heads_kernel<<<NN, 256, 0, stream>>>(hin, pin, FW1, FB1, FW2, FB2, CW1G, CB1G, CW2G, CB2G,
                                       SW, SB, IW, At, Bt, d_out, flag);
  scores_kernel<<<(3 * NN * KI + 255) / 256, 256, 0, stream>>>(
      pin, idx2, cnt2, At, Bt, IW, IB, d_out, flag);
}

// Round 11
// 1660.667 us; speedup vs baseline: 1.1135x; 1.0135x over previous
//
#include <hip/hip_runtime.h>
#include <hip/hip_bf16.h>

#define NN 4096
#define HD 128
#define KE 32
#define KI 20
#define BST 36   // LDS tile leading stride (32 cols + 4 pad, rows 16B-aligned)

// output element offsets
#define OFF_H   0
#define OFF_POS 524288
#define OFF_F   536576
#define OFF_S   548864
#define OFF_C   794624
#define OFF_ST  1056768

typedef unsigned short u16;
typedef unsigned long long u64;

__device__ __forceinline__ float b2f(u16 u) {
  union { unsigned int i; float f; } c; c.i = ((unsigned int)u) << 16; return c.f;
}
__device__ __forceinline__ float silu_f(float x) { return x / (1.f + __expf(-x)); }
__device__ __forceinline__ void stout(void* out, int fp32m, size_t i, float v) {
  if (fp32m) ((float*)out)[i] = v;
  else ((__hip_bfloat16*)out)[i] = __float2bfloat16(v);
}

// ---------------- dtype probe: are float inputs fp32 or bf16? ----------------
__global__ void probe_dtype(const u16* __restrict__ h, int* __restrict__ flag) {
  if (threadIdx.x == 0) atomicExch(flag, 0);
  __syncthreads();
  int bad = 0;
  for (int i = threadIdx.x; i < 8192; i += 256) {
    float v = b2f(h[i]);
    if (!(v > -1000.f && v < 1000.f)) bad = 1;  // catches NaN too
  }
  if (bad) atomicOr(flag, 1);  // 1 => inputs are fp32
}

// ---------------- convert all float tensors -> fp32 workspace ----------------
struct CvtTable {
  const void* src[25];
  int dstoff[25];
  int cnt[25];
};

__global__ void convert_all(CvtTable tab, float* __restrict__ wsf, const int* __restrict__ flag) {
  const int seg = blockIdx.y;
  const int i = blockIdx.x * 256 + threadIdx.x;
  if (i >= tab.cnt[seg]) return;
  float v;
  if (*flag) v = ((const float*)tab.src[seg])[i];
  else       v = b2f(((const u16*)tab.src[seg])[i]);
  wsf[tab.dstoff[seg] + i] = v;
}

// ---------------- graph boundaries from sorted batch ----------------
__global__ void graph_bounds(const int* __restrict__ batch, int* __restrict__ gstart) {
  int n = blockIdx.x * 256 + threadIdx.x;
  if (n >= NN) return;
  int v = batch[n];
  int pv = (n == 0) ? -1 : batch[n - 1];
  for (int b = pv + 1; b <= v; b++) gstart[b] = n;
  if (n == NN - 1) for (int b = v + 1; b <= 32; b++) gstart[b] = NN;
}

// ---------------- exact k-NN within cutoff (one wave per node) ----------------
// Numerics identical to the round-2 passing version; empty 64-candidate chunks
// are skipped via wave-uniform guards (skipped keys are ~0ull = never selected).
__global__ __launch_bounds__(256) void neigh_kernel(
    const float* __restrict__ pos, const int* __restrict__ batch,
    const int* __restrict__ gstart, int* __restrict__ idx, int* __restrict__ cnt,
    int Ksel, float cut2) {
  const int lane = threadIdx.x & 63;
  const int i = blockIdx.x * 4 + (threadIdx.x >> 6);
  const int b = batch[i];
  const int gs = gstart[b];
  const int ge = gstart[b + 1];
  const int span = ge - gs;  // wave-uniform
  const float px = pos[i * 3 + 0], py = pos[i * 3 + 1], pz = pos[i * 3 + 2];
  u64 key[16];
#pragma unroll
  for (int tq = 0; tq < 16; tq++) {
    u64 k64 = ~0ull;
    if (tq * 64 < span) {
      int j = gs + tq * 64 + lane;
      if (j < ge && j != i) {
        float dx = px - pos[j * 3 + 0];
        float dy = py - pos[j * 3 + 1];
        float dz = pz - pos[j * 3 + 2];
        float d2 = dx * dx + dy * dy + dz * dz;
        if (d2 <= cut2) k64 = (((u64)__float_as_uint(d2)) << 32) | (unsigned int)j;
      }
    }
    key[tq] = k64;
  }
  u64 thresh = 0;  // inclusive lower bound for next extraction
  int myidx = i;   // self index for invalid slots (masked downstream)
  int mycnt = 0;
  for (int s = 0; s < Ksel; s++) {
    u64 m = ~0ull;
#pragma unroll
    for (int tq = 0; tq < 16; tq++) {
      if (tq * 64 < span) {
        u64 kk = key[tq];
        if (kk >= thresh && kk < m) m = kk;
      }
    }
    for (int off = 32; off > 0; off >>= 1) {
      u64 o = __shfl_down(m, (unsigned)off, 64);
      if (o < m) m = o;
    }
    m = __shfl(m, 0, 64);
    if (m != ~0ull) {
      if (lane == s) myidx = (int)(m & 0xffffffffu);
      mycnt++;
      thresh = m + 1;
    } else break;
  }
  if (lane < Ksel) idx[i * Ksel + lane] = myidx;
  if (lane == 0) cnt[i] = mycnt;
}

// 4-output x 4-edge register-tiled stage core.
// Per-(e,o) fp chain identical to rounds 2/6/7/10: acc = base(o); f-ascending
// fmaf — bit-exact (unroll factor does not change per-accumulator op order).
// x from LDS (1 ds_read_b128/f, broadcast), w from global (1 dwordx4/f).
// unroll 8 widens the scheduler window; __launch_bounds__(256,4) on the
// caller pins VGPR <= 64 so the compiler pipelines only as far as fits
// without crossing the occupancy cliff (m69: waves/CU halve past 64 VGPR;
// r9's manual pipeline hit 88 VGPR and regressed).
__device__ __forceinline__ void stage16(const float* __restrict__ Wg, int o4, int e0,
                                        const float* X, const float base[4],
                                        float res[4][4]) {
  float acc[4][4];
#pragma unroll
  for (int oj = 0; oj < 4; oj++) {
    acc[oj][0] = base[oj]; acc[oj][1] = base[oj];
    acc[oj][2] = base[oj]; acc[oj][3] = base[oj];
  }
  const float* wp = Wg + o4;
#pragma unroll 8
  for (int f = 0; f < HD; f++) {
    float4 w = *(const float4*)(wp + (size_t)f * HD);
    float4 x = *(const float4*)(X + f * BST + e0);
    acc[0][0] = fmaf(w.x, x.x, acc[0][0]); acc[0][1] = fmaf(w.x, x.y, acc[0][1]);
    acc[0][2] = fmaf(w.x, x.z, acc[0][2]); acc[0][3] = fmaf(w.x, x.w, acc[0][3]);
    acc[1][0] = fmaf(w.y, x.x, acc[1][0]); acc[1][1] = fmaf(w.y, x.y, acc[1][1]);
    acc[1][2] = fmaf(w.y, x.z, acc[1][2]); acc[1][3] = fmaf(w.y, x.w, acc[1][3]);
    acc[2][0] = fmaf(w.z, x.x, acc[2][0]); acc[2][1] = fmaf(w.z, x.y, acc[2][1]);
    acc[2][2] = fmaf(w.z, x.z, acc[2][2]); acc[2][3] = fmaf(w.z, x.w, acc[2][3]);
    acc[3][0] = fmaf(w.w, x.x, acc[3][0]); acc[3][1] = fmaf(w.w, x.y, acc[3][1]);
    acc[3][2] = fmaf(w.w, x.z, acc[3][2]); acc[3][3] = fmaf(w.w, x.w, acc[3][3]);
  }
#pragma unroll
  for (int oj = 0; oj < 4; oj++) {
    res[oj][0] = acc[oj][0]; res[oj][1] = acc[oj][1];
    res[oj][2] = acc[oj][2]; res[oj][3] = acc[oj][3];
  }
}

// ---------------- one EGNN layer, one block per node ----------------
__global__ __launch_bounds__(256, 4) void egnn_layer(
    const float* __restrict__ h_in, const float* __restrict__ pos_in,
    float* __restrict__ h_out, float* __restrict__ pos_out,
    const int* __restrict__ idx, const int* __restrict__ cnt,
    const float* __restrict__ ew1, const float* __restrict__ eb1,
    const float* __restrict__ ew2, const float* __restrict__ eb2,
    const float* __restrict__ cw1, const float* __restrict__ cb1,
    const float* __restrict__ cw2,
    const float* __restrict__ nw1, const float* __restrict__ nb1,
    const float* __restrict__ nw2, const float* __restrict__ nb2) {
  __shared__ __align__(16) float bufA[HD * BST];
  __shared__ __align__(16) float bufB[HD * BST];
  __shared__ float hi_s[HD], hpart[HD], msum_s[HD], u_s[HD], red_s[256];
  __shared__ float rel_s[3][KE], d2_s[KE], mf_s[KE], ce_s[KE];
  __shared__ int idx_s[KE];

  const int i = blockIdx.x;
  const int t = threadIdx.x;

  if (t < KE) idx_s[t] = idx[i * KE + t];
  if (t >= 128) hi_s[t - 128] = h_in[(size_t)i * HD + (t - 128)];
  __syncthreads();

  const int cn = cnt[i];
  const int NCH = (cn + 3) >> 2;                    // valid 4-edge chunks (1..8)
  // round-7 mapping: og=t&31 (4-output tile), ec=t>>5 (4-edge chunk).
  // Waves own adjacent chunk pairs -> on sparse layers whole waves skip the
  // f-loop via execz (chunk pairs {0,1},{2,3},{4,5},{6,7}).
  const int og = t & 31, ec = t >> 5;
  const int o4 = og * 4, e0 = ec * 4;
  const bool active = (ec < NCH);

  if (t < KE) {
    int j = idx_s[t];
    float rx = pos_in[i * 3 + 0] - pos_in[j * 3 + 0];
    float ry = pos_in[i * 3 + 1] - pos_in[j * 3 + 1];
    float rz = pos_in[i * 3 + 2] - pos_in[j * 3 + 2];
    rel_s[0][t] = rx; rel_s[1][t] = ry; rel_s[2][t] = rz;
    d2_s[t] = rx * rx + ry * ry + rz * rz;
    mf_s[t] = (t < cn) ? 1.0f : 0.0f;
  }
  // gather hj -> bufA[f][e]
  {
    const int e = t & 31, f0 = (t >> 5) * 16;
    const int j = idx_s[e];
    const float4* src = (const float4*)(h_in + (size_t)j * HD + f0);
#pragma unroll
    for (int qq = 0; qq < 4; qq++) {
      float4 v = src[qq];
      int fb = f0 + qq * 4;
      bufA[(fb + 0) * BST + e] = v.x;
      bufA[(fb + 1) * BST + e] = v.y;
      bufA[(fb + 2) * BST + e] = v.z;
      bufA[(fb + 3) * BST + e] = v.w;
    }
  }
  // hpart[o] = hi . ew1[0:128, o]   (edge-invariant half of edge MLP1)
  {
    const int oo = t & 127, fb = (t >> 7) * 64;
    float hp = 0.f;
#pragma unroll 4
    for (int f = fb; f < fb + 64; f++) hp = fmaf(hi_s[f], ew1[f * HD + oo], hp);
    red_s[t] = hp;
  }
  __syncthreads();
  if (t < HD) hpart[t] = red_s[t] + red_s[t + 128] + eb1[t];
  __syncthreads();

  // ---- stage B: m1 = silu(hpart + hj @ ew1[128:256] + d2*ew1[256]) -> bufB ----
  if (active) {
    float base[4] = {hpart[o4], hpart[o4 + 1], hpart[o4 + 2], hpart[o4 + 3]};
    float res[4][4];
    stage16(ew1 + 128 * HD, o4, e0, bufA, base, res);
    float4 w256 = *(const float4*)(ew1 + 256 * HD + o4);
    float w2a[4] = {w256.x, w256.y, w256.z, w256.w};
#pragma unroll
    for (int oj = 0; oj < 4; oj++) {
      float4 s;
      s.x = silu_f(fmaf(w2a[oj], d2_s[e0 + 0], res[oj][0]));
      s.y = silu_f(fmaf(w2a[oj], d2_s[e0 + 1], res[oj][1]));
      s.z = silu_f(fmaf(w2a[oj], d2_s[e0 + 2], res[oj][2]));
      s.w = silu_f(fmaf(w2a[oj], d2_s[e0 + 3], res[oj][3]));
      *(float4*)(bufB + (o4 + oj) * BST + e0) = s;
    }
  }
  __syncthreads();

  // ---- stage C: m2 = mask ? silu(m1 @ ew2 + eb2) : 0 -> bufA (pad chunks zeroed) ----
  {
    if (active) {
      float base[4] = {eb2[o4], eb2[o4 + 1], eb2[o4 + 2], eb2[o4 + 3]};
      float res[4][4];
      stage16(ew2, o4, e0, bufB, base, res);
#pragma unroll
      for (int oj = 0; oj < 4; oj++) {
        float4 s;
        s.x = (mf_s[e0 + 0] != 0.f) ? silu_f(res[oj][0]) : 0.f;
        s.y = (mf_s[e0 + 1] != 0.f) ? silu_f(res[oj][1]) : 0.f;
        s.z = (mf_s[e0 + 2] != 0.f) ? silu_f(res[oj][2]) : 0.f;
        s.w = (mf_s[e0 + 3] != 0.f) ? silu_f(res[oj][3]) : 0.f;
        *(float4*)(bufA + (o4 + oj) * BST + e0) = s;
      }
    } else {
      // zero pad chunks so msum's add chain matches bit-exactly
      float4 z; z.x = 0.f; z.y = 0.f; z.z = 0.f; z.w = 0.f;
#pragma unroll
      for (int oj = 0; oj < 4; oj++) *(float4*)(bufA + (o4 + oj) * BST + e0) = z;
    }
  }
  __syncthreads();

  // ---- stage D: c1 = silu(m2 @ cw1 + cb1) -> bufB ----
  if (active) {
    float base[4] = {cb1[o4], cb1[o4 + 1], cb1[o4 + 2], cb1[o4 + 3]};
    float res[4][4];
    stage16(cw1, o4, e0, bufA, base, res);
#pragma unroll
    for (int oj = 0; oj < 4; oj++) {
      float4 s;
      s.x = silu_f(res[oj][0]); s.y = silu_f(res[oj][1]);
      s.z = silu_f(res[oj][2]); s.w = silu_f(res[oj][3]);
      *(float4*)(bufB + (o4 + oj) * BST + e0) = s;
    }
  }
  __syncthreads();

  // ---- c[e] = c1[e] . cw2 ; pos update ----
  {
    const int e = t & 31, oc = t >> 5;
    float p = 0.f;
#pragma unroll 4
    for (int u = 0; u < 16; u++) {
      int oo = oc * 16 + u;
      p = fmaf(bufB[oo * BST + e], cw2[oo], p);
    }
    red_s[t] = p;
  }
  __syncthreads();
  if (t < KE) {
    float c = 0.f;
#pragma unroll
    for (int u = 0; u < 8; u++) c += red_s[u * 32 + t];
    ce_s[t] = (t < cn) ? c : 0.f;
  }
  __syncthreads();
  if (t < 3) {
    float s = 0.f;
#pragma unroll
    for (int e = 0; e < KE; e++) s = fmaf(rel_s[t][e], ce_s[e], s);
    float cntf = fmaxf((float)cn, 1.f);
    pos_out[i * 3 + t] = pos_in[i * 3 + t] + s / cntf;
  }
  // ---- msum[o] = sum_e m2[e][o] ----
  {
    const int oo = t & 127, ehh = t >> 7;
    float p = 0.f;
#pragma unroll
    for (int u = 0; u < 16; u++) p += bufA[oo * BST + ehh * 16 + u];
    red_s[t] = p;
  }
  __syncthreads();
  if (t < HD) msum_s[t] = red_s[t] + red_s[t + 128];
  __syncthreads();
  // ---- node MLP1 ----
  {
    const int oo = t & 127, ph = t >> 7;
    const float* src = ph ? msum_s : hi_s;
    const float* Wp = nw1 + (size_t)ph * 128 * HD + oo;
    float p = 0.f;
#pragma unroll 4
    for (int f = 0; f < 128; f++) p = fmaf(src[f], Wp[f * HD], p);
    red_s[t] = p;
  }
  __syncthreads();
  if (t < HD) u_s[t] = silu_f(red_s[t] + red_s[t + 128] + nb1[t]);
  __syncthreads();
  // ---- node MLP2 + residual ----
  {
    const int oo = t & 127, ph = t >> 7;
    const float* Wp = nw2 + (size_t)ph * 64 * HD + oo;
    float p = 0.f;
#pragma unroll 4
    for (int f = 0; f < 64; f++) p = fmaf(u_s[ph * 64 + f], Wp[f * HD], p);
    red_s[t] = p;
  }
  __syncthreads();
  if (t < HD) h_out[(size_t)i * HD + t] = hi_s[t] + red_s[t] + red_s[t + 128] + nb2[t];
}

// ---------------- final heads (per node) ----------------
__global__ __launch_bounds__(256) void heads_kernel(
    const float* __restrict__ h, const float* __restrict__ pos,
    const float* __restrict__ fw1, const float* __restrict__ fb1,
    const float* __restrict__ fw2, const float* __restrict__ fb2,
    const float* __restrict__ cw1g, const float* __restrict__ cb1g,
    const float* __restrict__ cw2g, const float* __restrict__ cb2g,
    const float* __restrict__ sw, const float* __restrict__ sb,
    const float* __restrict__ iw,
    float* __restrict__ At, float* __restrict__ Bt,
    void* __restrict__ out, const int* __restrict__ flag) {
  __shared__ float hi_s[HD], v1[HD], red_s[256];
  const int i = blockIdx.x, t = threadIdx.x;
  const int fm = *flag;
  if (t < HD) hi_s[t] = h[(size_t)i * HD + t];
  __syncthreads();
  const int o = t & 127, ph = t >> 7;
  // forces MLP1
  {
    float p = 0.f;
#pragma unroll 4
    for (int f = ph * 64; f < ph * 64 + 64; f++) p = fmaf(hi_s[f], fw1[f * HD + o], p);
    red_s[t] = p;
  }
  __syncthreads();
  if (t < HD) v1[t] = tanhf(red_s[t] + red_s[t + 128] + fb1[t]);
  __syncthreads();
  if (t < 3) {
    float p = 0.f;
    for (int f = 0; f < HD; f++) p = fmaf(v1[f], fw2[f * 3 + t], p);
    stout(out, fm, OFF_F + (size_t)i * 3 + t, p + fb2[t]);
  }
  __syncthreads();
  // conformer MLP1
  {
    float p = 0.f;
#pragma unroll 4
    for (int f = ph * 64; f < ph * 64 + 64; f++) p = fmaf(hi_s[f], cw1g[f * HD + o], p);
    red_s[t] = p;
  }
  __syncthreads();
  if (t < HD) v1[t] = fmaxf(red_s[t] + red_s[t + 128] + cb1g[t], 0.f);
  __syncthreads();
  // conformer MLP2
  {
    const int oo = t & 63, pc = t >> 6;
    float p = 0.f;
#pragma unroll 4
    for (int f = pc * 32; f < pc * 32 + 32; f++) p = fmaf(v1[f], cw2g[f * 64 + oo], p);
    red_s[t] = p;
  }
  __syncthreads();
  if (t < 64)
    stout(out, fm, OFF_C + (size_t)i * 64 + t,
          red_s[t] + red_s[t + 64] + red_s[t + 128] + red_s[t + 192] + cb2g[t]);
  __syncthreads();
  // steric
  if (t < HD) red_s[t] = hi_s[t] * sw[t];
  __syncthreads();
  if (t == 0) {
    float p = 0.f;
    for (int f = 0; f < HD; f++) p += red_s[f];
    stout(out, fm, OFF_ST + (size_t)i, p + sb[0]);
  }
  __syncthreads();
  // interaction head per-node dots
  {
    const int g = t >> 5, l = t & 31;
    float p = 0.f;
    if (g < 6) {
      const int tt = g >> 1, half = g & 1;
#pragma unroll
      for (int r2 = 0; r2 < 4; r2++)
        p = fmaf(hi_s[l * 4 + r2], iw[tt * 258 + half * 128 + l * 4 + r2], p);
    }
    red_s[t] = p;
  }
  __syncthreads();
  if (t < 6) {
    float p = 0.f;
    for (int l = 0; l < 32; l++) p += red_s[t * 32 + l];
    const int tt = t >> 1;
    if ((t & 1) == 0) At[tt * NN + i] = p;
    else Bt[tt * NN + i] = p;
  }
  if (t < HD) stout(out, fm, OFF_H + (size_t)i * HD + t, hi_s[t]);
  if (t >= 128 && t < 131) stout(out, fm, OFF_POS + (size_t)i * 3 + (t - 128), pos[i * 3 + (t - 128)]);
}

// ---------------- interaction scores ----------------
__global__ void scores_kernel(const float* __restrict__ pos, const int* __restrict__ idx2,
                              const int* __restrict__ cnt2, const float* __restrict__ At,
                              const float* __restrict__ Bt, const float* __restrict__ iw,
                              const float* __restrict__ ib, void* __restrict__ out,
                              const int* __restrict__ flag) {
  int tid = blockIdx.x * 256 + threadIdx.x;
  if (tid >= 3 * NN * KI) return;
  const int fm = *flag;
  const int tt = tid / (NN * KI);
  const int r = tid % (NN * KI);
  const int n = r / KI;
  const int k = r % KI;
  float v = 0.f;
  if (k < cnt2[n]) {
    int j = idx2[n * KI + k];
    float dx = pos[n * 3 + 0] - pos[j * 3 + 0];
    float dy = pos[n * 3 + 1] - pos[j * 3 + 1];
    float dz = pos[n * 3 + 2] - pos[j * 3 + 2];
    float d2 = dx * dx + dy * dy + dz * dz;
    float dist = sqrtf(d2 + 1e-12f);
    float s = At[tt * NN + n] + Bt[tt * NN + j] + dist * iw[tt * 258 + 256] +
              (dist * 0.1f) * iw[tt * 258 + 257] + ib[tt];
    v = 1.f / (1.f + __expf(-s));
  }
  stout(out, fm, OFF_S + (size_t)tid, v);
}

extern "C" void kernel_launch(void* const* d_in, const int* in_sizes, int n_in,
                              void* d_out, int out_size, void* d_ws, size_t ws_size,
                              hipStream_t stream) {
  (void)in_sizes; (void)n_in; (void)out_size; (void)ws_size;

  float* wsf = (float*)d_ws;
  float* h_a = wsf + 0;             // 524288
  float* pos_a = wsf + 524288;      // 12288
  float* h_b = wsf + 536576;        // 524288
  float* pos_b = wsf + 1060864;     // 12288
  float* At = wsf + 1073152;        // 12288
  float* Bt = wsf + 1085440;        // 12288
  const int W0 = 1097728;

  static const int wcnt[23] = {197376, 768, 98304, 768, 98304, 768, 768,
                               196608, 768, 98304, 768, 16384, 128, 384, 3,
                               774, 3, 16384, 128, 8192, 64, 128, 1};
  int woff[23];
  {
    int o = W0;
    for (int k = 0; k < 23; k++) { woff[k] = o; o += wcnt[k]; }
  }
  const int IOFF = woff[22] + wcnt[22];
  int* ibase = (int*)d_ws;
  int* idx1 = ibase + IOFF;
  int* cnt1 = idx1 + NN * KE;
  int* idx2 = cnt1 + NN;
  int* cnt2 = idx2 + NN * KI;
  int* gstart = cnt2 + NN;
  int* flag = gstart + 33;

  const float* EW1 = wsf + woff[0];
  const float* EB1 = wsf + woff[1];
  const float* EW2 = wsf + woff[2];
  const float* EB2 = wsf + woff[3];
  const float* CW1 = wsf + woff[4];
  const float* CB1 = wsf + woff[5];
  const float* CW2 = wsf + woff[6];
  const float* NW1 = wsf + woff[7];
  const float* NB1 = wsf + woff[8];
  const float* NW2 = wsf + woff[9];
  const float* NB2 = wsf + woff[10];
  const float* FW1 = wsf + woff[11];
  const float* FB1 = wsf + woff[12];
  const float* FW2 = wsf + woff[13];
  const float* FB2 = wsf + woff[14];
  const float* IW = wsf + woff[15];
  const float* IB = wsf + woff[16];
  const float* CW1G = wsf + woff[17];
  const float* CB1G = wsf + woff[18];
  const float* CW2G = wsf + woff[19];
  const float* CB2G = wsf + woff[20];
  const float* SW = wsf + woff[21];
  const float* SB = wsf + woff[22];

  probe_dtype<<<1, 256, 0, stream>>>((const u16*)d_in[0], flag);

  CvtTable tab;
  tab.src[0] = d_in[0]; tab.dstoff[0] = 0;       tab.cnt[0] = NN * HD;
  tab.src[1] = d_in[1]; tab.dstoff[1] = 524288;  tab.cnt[1] = NN * 3;
  for (int k = 0; k < 23; k++) {
    tab.src[2 + k] = d_in[3 + k];
    tab.dstoff[2 + k] = woff[k];
    tab.cnt[2 + k] = wcnt[k];
  }
  {
    dim3 g((NN * HD + 255) / 256, 25, 1);
    convert_all<<<g, 256, 0, stream>>>(tab, wsf, flag);
  }

  const int* batch = (const int*)d_in[2];
  graph_bounds<<<NN / 256, 256, 0, stream>>>(batch, gstart);

  const float cut2s[3] = {9.f, 36.f, 100.f};
  float *hin = h_a, *pin = pos_a, *hout = h_b, *pout = pos_b;
  for (int l = 0; l < 6; l++) {
    if ((l & 1) == 0)
      neigh_kernel<<<NN / 4, 256, 0, stream>>>(pin, batch, gstart, idx1, cnt1, KE, cut2s[l >> 1]);
    egnn_layer<<<NN, 256, 0, stream>>>(
        hin, pin, hout, pout, idx1, cnt1,
        EW1 + (size_t)l * 257 * HD, EB1 + (size_t)l * HD,
        EW2 + (size_t)l * HD * HD, EB2 + (size_t)l * HD,
        CW1 + (size_t)l * HD * HD, CB1 + (size_t)l * HD,
        CW2 + (size_t)l * HD,
        NW1 + (size_t)l * 256 * HD, NB1 + (size_t)l * HD,
        NW2 + (size_t)l * HD * HD, NB2 + (size_t)l * HD);
    float* th = hin; hin = hout; hout = th;
    float* tp = pin; pin = pout; pout = tp;
  }
  neigh_kernel<<<NN / 4, 256, 0, stream>>>(pin, batch, gstart, idx2, cnt2, KI, 100.f);
  heads_kernel<<<NN, 256, 0, stream>>>(hin, pin, FW1, FB1, FW2, FB2, CW1G, CB1G, CW2G, CB2G,
                                       SW, SB, IW, At, Bt, d_out, flag);
  scores_kernel<<<(3 * NN * KI + 255) / 256, 256, 0, stream>>>(
      pin, idx2, cnt2, At, Bt, IW, IB, d_out, flag);
}